// Round 7
// baseline (165.238 us; speedup 1.0000x reference)
//
#include <hip/hip_runtime.h>
#include <hip/hip_bf16.h>

#define NPOS 131072   // 32*64*64 positions per batch

typedef __attribute__((ext_vector_type(8))) short short8;
typedef __attribute__((ext_vector_type(4))) float floatx4;
typedef unsigned int uint32;

__device__ __forceinline__ unsigned short bf16b(float v) {
    __hip_bfloat16 h = __float2bfloat16(v);
    return __builtin_bit_cast(unsigned short, h);
}
__device__ __forceinline__ uint32 cvtpk(float lo, float hi) {
    uint32 r;
    asm("v_cvt_pk_bf16_f32 %0, %1, %2" : "=v"(r) : "v"(lo), "v"(hi));
    return r;
}
#if __has_builtin(__builtin_amdgcn_exp2f)
#define EXP2(x) __builtin_amdgcn_exp2f(x)
#else
#define EXP2(x) exp2f(x)
#endif
#if __has_builtin(__builtin_amdgcn_rcpf)
#define RCPF(x) __builtin_amdgcn_rcpf(x)
#else
#define RCPF(x) (1.0f / (x))
#endif

// ---------------- K0: wq -> bf16*QS, wout -> bf16 (global operand buffers) ----------------
__global__ void k_prep_w(const float* __restrict__ wq, const float* __restrict__ wout,
                         unsigned short* __restrict__ wqb, unsigned short* __restrict__ woutb) {
    const float QS = 0.36067376022224085f;   // 0.25 * log2(e)
    int gid = blockIdx.x * 256 + threadIdx.x;   // 0..4095
    wqb[gid]   = bf16b(wq[gid] * QS);
    woutb[gid] = bf16b(wout[gid]);
}

// ---------------- K1: wkv[oc][ic][term] f32 -> wtb[ic][oc][term] bf16 ----------------
__global__ void k_prep_wkvb(const float* __restrict__ wkv, unsigned short* __restrict__ wtb) {
    int gid = blockIdx.x * 256 + threadIdx.x;
    int ic = gid >> 14;
    int oc = (gid >> 7) & 127;
    float4 v = *(const float4*)(wkv + ((size_t)(oc * 64 + ic)) * 512 + (size_t)(gid & 127) * 4);
    uint32* dst = (uint32*)(wtb + (size_t)gid * 4);
    dst[0] = cvtpk(v.x, v.y);
    dst[1] = cvtpk(v.z, v.w);
}

// ---------------- K2: conv as bf16 MFMA GEMM, split-K over ic (unchanged, passing) ----------------
__global__ __launch_bounds__(256) void k_conv_mfma(const float* __restrict__ x,
                                                   const unsigned short* __restrict__ wtb,
                                                   float* __restrict__ partial) {
    __shared__ __align__(16) unsigned short As[64 * 72];
    __shared__ __align__(16) unsigned short Bs[128 * 72];
    const int bid = blockIdx.x;
    const int ic = bid & 63;
    const int b  = (bid >> 6) & 1;
    const int pz = bid >> 7;
    const int tid = threadIdx.x;
    const int lane = tid & 63, wv = tid >> 6;
    const int lc = lane & 15, lg = lane >> 4;

    floatx4 acc[4][2];
#pragma unroll
    for (int mt = 0; mt < 4; ++mt)
#pragma unroll
        for (int n = 0; n < 2; ++n) acc[mt][n] = {0.f, 0.f, 0.f, 0.f};

    const float* xp = x + ((size_t)b * 64 + ic) * NPOS + (size_t)pz * 8 * 4096;
    const unsigned short* wp = wtb + (size_t)ic * 128 * 512;

    for (int rz = 0; rz < 8; ++rz) {
        __syncthreads();
        const float* plane = xp + (size_t)rz * 4096;
#pragma unroll
        for (int t2 = 0; t2 < 4; ++t2) {
            int e = (t2 * 256 + tid) * 4;
            int y = e >> 6, x0 = e & 63;
            int p = ((y >> 3) << 3) + (x0 >> 3);
            int k = ((y & 7) << 3) + (x0 & 7);
            float4 v = *(const float4*)(plane + e);
            uint32* dst = (uint32*)&As[p * 72 + k];
            dst[0] = cvtpk(v.x, v.y);
            dst[1] = cvtpk(v.z, v.w);
        }
        {
            int oc = tid >> 1, hf = tid & 1;
            const uint4* src = (const uint4*)(wp + (size_t)oc * 512 + rz * 64 + hf * 32);
            uint4* dst = (uint4*)&Bs[oc * 72 + hf * 32];
#pragma unroll
            for (int r = 0; r < 4; ++r) dst[r] = src[r];
        }
        __syncthreads();
#pragma unroll
        for (int ks = 0; ks < 2; ++ks) {
            short8 bb0 = *(const short8*)&Bs[((wv * 2 + 0) * 16 + lc) * 72 + ks * 32 + lg * 8];
            short8 bb1 = *(const short8*)&Bs[((wv * 2 + 1) * 16 + lc) * 72 + ks * 32 + lg * 8];
#pragma unroll
            for (int mt = 0; mt < 4; ++mt) {
                short8 a = *(const short8*)&As[(mt * 16 + lc) * 72 + ks * 32 + lg * 8];
                acc[mt][0] = __builtin_amdgcn_mfma_f32_16x16x32_bf16(a, bb0, acc[mt][0], 0, 0, 0);
                acc[mt][1] = __builtin_amdgcn_mfma_f32_16x16x32_bf16(a, bb1, acc[mt][1], 0, 0, 0);
            }
        }
    }
    float* pb = partial + (((size_t)ic * 2 + b) * 256 + pz * 64) * 128;
#pragma unroll
    for (int mt = 0; mt < 4; ++mt)
#pragma unroll
        for (int ntl = 0; ntl < 2; ++ntl) {
            int oc = (wv * 2 + ntl) * 16 + lc;
#pragma unroll
            for (int r = 0; r < 4; ++r) {
                int m = mt * 16 + lg * 4 + r;
                pb[(size_t)m * 128 + oc] = acc[mt][ntl][r];
            }
        }
}

// ---------------- K3: reduce over ic; K -> bf16 [b][h][256][16], V -> bf16 [b][h][16][256] ----------------
__global__ void k_reduce(const float* __restrict__ partial,
                         unsigned short* __restrict__ kt, unsigned short* __restrict__ vt) {
    int gid = blockIdx.x * 256 + threadIdx.x;
    int oc = gid & 127;
    int bp = gid >> 7;          // b*256 + j
    int b = bp >> 8;
    int j = bp & 255;
    const float* p = partial + (size_t)bp * 128 + oc;
    float s = 0.f;
#pragma unroll 8
    for (int ic = 0; ic < 64; ++ic) s += p[(size_t)ic * 65536];
    int h = (oc & 63) >> 4, i = oc & 15;
    if (oc < 64)
        kt[(((size_t)b * 4 + h) * 256 + j) * 16 + i] = bf16b(s);
    else
        vt[(((size_t)b * 4 + h) * 16 + i) * 256 + j] = bf16b(s);
}

// ---------------- K4: fused attention, wave-local LDS, global-fed K/V/weights ----------------
// grid 4096 = b(2) x 2048 n-blocks of 64; 256 thr (4 waves); wave owns 16 query rows.
// Compute graph identical to round-4's verified k_attn_mfma; only data movement changed.
__global__ __launch_bounds__(256, 3) void k_attn3(
    const float* __restrict__ x, const unsigned short* __restrict__ wqb,
    const unsigned short* __restrict__ woutb, const unsigned short* __restrict__ kt,
    const unsigned short* __restrict__ vt, float* __restrict__ out)
{
    __shared__ __align__(16) unsigned short s_at[4][16 * 72];   // per-wave x^T then att [n][c]
    __shared__ __align__(16) unsigned short s_qb[4][16 * 136];  // per-wave Q [n][h*32+i], pads zero
    __shared__ __align__(16) unsigned short s_pb[4][16 * 136];  // per-wave P half [n][j0..127]; later yb f32 [64][68]
    __shared__ float s_l[4][16];

    const int tid = threadIdx.x;
    const int b = blockIdx.x >> 11;
    const int n_base = (blockIdx.x & 2047) << 6;
    const int lane = tid & 63;
    const int wv = tid >> 6;
    const int lc = lane & 15;
    const int lg = lane >> 4;

    unsigned short* at = s_at[wv];
    unsigned short* qb = s_qb[wv];
    unsigned short* pb = s_pb[wv];

    // ---- load x rows (wave-local): n = n_base + wv*16 + lc, channels lg*16..+15 ----
    {
        const float* xb = x + ((size_t)b << 23) + n_base + wv * 16 + lc;
        int c0 = lg * 16;
        uint32* xrow = (uint32*)&at[lc * 72 + c0];
#pragma unroll
        for (int r = 0; r < 8; ++r) {
            float v0 = xb[(size_t)(c0 + 2 * r) << 17];
            float v1 = xb[(size_t)(c0 + 2 * r + 1) << 17];
            xrow[r] = cvtpk(v0, v1);
        }
    }
    // ---- zero Q buffer (pad halves must be 0) ----
    {
        uint32* q32 = (uint32*)qb;
#pragma unroll
        for (int r = 0; r < 17; ++r) q32[r * 64 + lane] = 0;
    }

    // ---- Q projection: MFMA(A = x^T from LDS, B = wq from global) ----
#pragma unroll
    for (int ot = 0; ot < 4; ++ot) {
        floatx4 c = {0.f, 0.f, 0.f, 0.f};
#pragma unroll
        for (int ks = 0; ks < 2; ++ks) {
            short8 a  = *(const short8*)&at[lc * 72 + ks * 32 + lg * 8];
            short8 bb = *(const short8*)(wqb + (ot * 16 + lc) * 64 + ks * 32 + lg * 8);
            c = __builtin_amdgcn_mfma_f32_16x16x32_bf16(a, bb, c, 0, 0, 0);
        }
#pragma unroll
        for (int r = 0; r < 4; ++r)
            qb[(lg * 4 + r) * 136 + ot * 32 + lc] = bf16b(c[r]);
    }

    // ---- heads: QK^T (padded K, zero Q-pads) -> exp2 -> P half in LDS -> PV accumulate ----
#pragma unroll 1
    for (int h = 0; h < 4; ++h) {
        const unsigned short* kh = kt + (((size_t)b * 4 + h) << 12);
        const unsigned short* vh = vt + (((size_t)b * 4 + h) << 12);
        short8 qfrag = *(const short8*)&qb[lc * 136 + h * 32 + lg * 8];
        float lp = 0.f;
        floatx4 pv = {0.f, 0.f, 0.f, 0.f};
#pragma unroll 1
        for (int half = 0; half < 2; ++half) {
            uint32* prow = (uint32*)&pb[lc * 136];
#pragma unroll
            for (int jt = 0; jt < 8; ++jt) {
                int j0 = half * 128 + jt * 16;
                short8 a = *(const short8*)(kh + (size_t)(j0 + lc) * 16 + (lg & 1) * 8);
                floatx4 c = {0.f, 0.f, 0.f, 0.f};
                c = __builtin_amdgcn_mfma_f32_16x16x32_bf16(a, qfrag, c, 0, 0, 0);
                float p0 = EXP2(c[0]); float p1 = EXP2(c[1]);
                float p2 = EXP2(c[2]); float p3 = EXP2(c[3]);
                lp += (p0 + p1) + (p2 + p3);
                prow[jt * 8 + lg * 2 + 0] = cvtpk(p0, p1);
                prow[jt * 8 + lg * 2 + 1] = cvtpk(p2, p3);
            }
            // PV over this half's 128 keys (A = P from wave-local LDS, B = V^T from global)
#pragma unroll
            for (int ks = 0; ks < 4; ++ks) {
                short8 a  = *(const short8*)&pb[lc * 136 + ks * 32 + lg * 8];
                short8 bb = *(const short8*)(vh + (size_t)lc * 256 + half * 128 + ks * 32 + lg * 8);
                pv = __builtin_amdgcn_mfma_f32_16x16x32_bf16(a, bb, pv, 0, 0, 0);
            }
        }
        lp += __shfl_xor(lp, 16, 64);
        lp += __shfl_xor(lp, 32, 64);
        if (lane < 16) s_l[wv][lane] = lp;
#pragma unroll
        for (int r = 0; r < 4; ++r) {
            float rl = RCPF(s_l[wv][lg * 4 + r]);
            at[(lg * 4 + r) * 72 + h * 16 + lc] = bf16b(pv[r] * rl);
        }
    }

    __syncthreads();   // all waves done with s_pb before aliasing it as yb

    // ---- out projection: MFMA(A = att from LDS, B = wout from global); y -> yb[o][n] ----
    float* yb = (float*)&s_pb[0][0];   // [64][68] f32 = 17408 B (= sizeof s_pb)
#pragma unroll
    for (int ot = 0; ot < 4; ++ot) {
        floatx4 c = {0.f, 0.f, 0.f, 0.f};
#pragma unroll
        for (int ks = 0; ks < 2; ++ks) {
            short8 a  = *(const short8*)&at[lc * 72 + ks * 32 + lg * 8];
            short8 bb = *(const short8*)(woutb + (ot * 16 + lc) * 64 + ks * 32 + lg * 8);
            c = __builtin_amdgcn_mfma_f32_16x16x32_bf16(a, bb, c, 0, 0, 0);
        }
#pragma unroll
        for (int r = 0; r < 4; ++r)
            yb[(ot * 16 + lc) * 68 + wv * 16 + lg * 4 + r] = c[r];
    }
    __syncthreads();

    // ---- coalesced copyout: 256B contiguous per o-row ----
    {
        int o = tid >> 2, nc = (tid & 3) * 16;
        float* dst = out + ((size_t)b << 23) + (size_t)o * 131072 + n_base + nc;
        const float* src = yb + o * 68 + nc;
#pragma unroll
        for (int i = 0; i < 4; ++i)
            *(float4*)(dst + i * 4) = *(const float4*)(src + i * 4);
    }
}

extern "C" void kernel_launch(void* const* d_in, const int* in_sizes, int n_in,
                              void* d_out, int out_size, void* d_ws, size_t ws_size,
                              hipStream_t stream) {
    const float* x    = (const float*)d_in[0];
    const float* wq   = (const float*)d_in[1];
    const float* wkv  = (const float*)d_in[2];
    const float* wout = (const float*)d_in[3];
    float* out = (float*)d_out;
    float* ws = (float*)d_ws;

    unsigned short* wtb = (unsigned short*)ws;              // [64][128][512] bf16 = 8 MB
    float* partial = ws + 2097152;                          // [64][2][256][128] f32 = 16 MB
    unsigned short* ktu = (unsigned short*)(ws + 6291456);  // [2][4][256][16] bf16
    unsigned short* vtu   = ktu + 32768;                    // [2][4][16][256] bf16
    unsigned short* wqb   = vtu + 32768;                    // [64][64] bf16
    unsigned short* woutb = wqb + 4096;                     // [64][64] bf16

    k_prep_w   <<<16,   256, 0, stream>>>(wq, wout, wqb, woutb);
    k_prep_wkvb<<<4096, 256, 0, stream>>>(wkv, wtb);
    k_conv_mfma<<<512,  256, 0, stream>>>(x, wtb, partial);
    k_reduce   <<<256,  256, 0, stream>>>(partial, ktu, vtu);
    k_attn3    <<<4096, 256, 0, stream>>>(x, wqb, woutb, ktu, vtu, out);
}

// Round 8
// 103.290 us; speedup vs baseline: 1.5997x; 1.5997x over previous
//
#include <hip/hip_runtime.h>
#include <hip/hip_bf16.h>

#define NPOS 131072   // 32*64*64 positions per batch

typedef __attribute__((ext_vector_type(8))) short short8;
typedef __attribute__((ext_vector_type(4))) float floatx4;
typedef unsigned int uint32;

__device__ __forceinline__ unsigned short bf16b(float v) {
    __hip_bfloat16 h = __float2bfloat16(v);
    return __builtin_bit_cast(unsigned short, h);
}
__device__ __forceinline__ uint32 cvtpk(float lo, float hi) {
    uint32 r;
    asm("v_cvt_pk_bf16_f32 %0, %1, %2" : "=v"(r) : "v"(lo), "v"(hi));
    return r;
}
#if __has_builtin(__builtin_amdgcn_exp2f)
#define EXP2(x) __builtin_amdgcn_exp2f(x)
#else
#define EXP2(x) exp2f(x)
#endif
#if __has_builtin(__builtin_amdgcn_rcpf)
#define RCPF(x) __builtin_amdgcn_rcpf(x)
#else
#define RCPF(x) (1.0f / (x))
#endif

// ---------------- K0: wq -> bf16*QS, wout -> bf16 (global operand buffers) ----------------
__global__ void k_prep_w(const float* __restrict__ wq, const float* __restrict__ wout,
                         unsigned short* __restrict__ wqb, unsigned short* __restrict__ woutb) {
    const float QS = 0.36067376022224085f;   // 0.25 * log2(e)
    int gid = blockIdx.x * 256 + threadIdx.x;   // 0..4095
    wqb[gid]   = bf16b(wq[gid] * QS);
    woutb[gid] = bf16b(wout[gid]);
}

// ---------------- K1: wkv[oc][ic][term] f32 -> wtb[ic][oc][term] bf16 ----------------
__global__ void k_prep_wkvb(const float* __restrict__ wkv, unsigned short* __restrict__ wtb) {
    int gid = blockIdx.x * 256 + threadIdx.x;
    int ic = gid >> 14;
    int oc = (gid >> 7) & 127;
    float4 v = *(const float4*)(wkv + ((size_t)(oc * 64 + ic)) * 512 + (size_t)(gid & 127) * 4);
    uint32* dst = (uint32*)(wtb + (size_t)gid * 4);
    dst[0] = cvtpk(v.x, v.y);
    dst[1] = cvtpk(v.z, v.w);
}

// ---------------- K2: conv as bf16 MFMA GEMM, split-K over ic (unchanged, passing) ----------------
__global__ __launch_bounds__(256) void k_conv_mfma(const float* __restrict__ x,
                                                   const unsigned short* __restrict__ wtb,
                                                   float* __restrict__ partial) {
    __shared__ __align__(16) unsigned short As[64 * 72];
    __shared__ __align__(16) unsigned short Bs[128 * 72];
    const int bid = blockIdx.x;
    const int ic = bid & 63;
    const int b  = (bid >> 6) & 1;
    const int pz = bid >> 7;
    const int tid = threadIdx.x;
    const int lane = tid & 63, wv = tid >> 6;
    const int lc = lane & 15, lg = lane >> 4;

    floatx4 acc[4][2];
#pragma unroll
    for (int mt = 0; mt < 4; ++mt)
#pragma unroll
        for (int n = 0; n < 2; ++n) acc[mt][n] = {0.f, 0.f, 0.f, 0.f};

    const float* xp = x + ((size_t)b * 64 + ic) * NPOS + (size_t)pz * 8 * 4096;
    const unsigned short* wp = wtb + (size_t)ic * 128 * 512;

    for (int rz = 0; rz < 8; ++rz) {
        __syncthreads();
        const float* plane = xp + (size_t)rz * 4096;
#pragma unroll
        for (int t2 = 0; t2 < 4; ++t2) {
            int e = (t2 * 256 + tid) * 4;
            int y = e >> 6, x0 = e & 63;
            int p = ((y >> 3) << 3) + (x0 >> 3);
            int k = ((y & 7) << 3) + (x0 & 7);
            float4 v = *(const float4*)(plane + e);
            uint32* dst = (uint32*)&As[p * 72 + k];
            dst[0] = cvtpk(v.x, v.y);
            dst[1] = cvtpk(v.z, v.w);
        }
        {
            int oc = tid >> 1, hf = tid & 1;
            const uint4* src = (const uint4*)(wp + (size_t)oc * 512 + rz * 64 + hf * 32);
            uint4* dst = (uint4*)&Bs[oc * 72 + hf * 32];
#pragma unroll
            for (int r = 0; r < 4; ++r) dst[r] = src[r];
        }
        __syncthreads();
#pragma unroll
        for (int ks = 0; ks < 2; ++ks) {
            short8 bb0 = *(const short8*)&Bs[((wv * 2 + 0) * 16 + lc) * 72 + ks * 32 + lg * 8];
            short8 bb1 = *(const short8*)&Bs[((wv * 2 + 1) * 16 + lc) * 72 + ks * 32 + lg * 8];
#pragma unroll
            for (int mt = 0; mt < 4; ++mt) {
                short8 a = *(const short8*)&As[(mt * 16 + lc) * 72 + ks * 32 + lg * 8];
                acc[mt][0] = __builtin_amdgcn_mfma_f32_16x16x32_bf16(a, bb0, acc[mt][0], 0, 0, 0);
                acc[mt][1] = __builtin_amdgcn_mfma_f32_16x16x32_bf16(a, bb1, acc[mt][1], 0, 0, 0);
            }
        }
    }
    float* pb = partial + (((size_t)ic * 2 + b) * 256 + pz * 64) * 128;
#pragma unroll
    for (int mt = 0; mt < 4; ++mt)
#pragma unroll
        for (int ntl = 0; ntl < 2; ++ntl) {
            int oc = (wv * 2 + ntl) * 16 + lc;
#pragma unroll
            for (int r = 0; r < 4; ++r) {
                int m = mt * 16 + lg * 4 + r;
                pb[(size_t)m * 128 + oc] = acc[mt][ntl][r];
            }
        }
}

// ---------------- K3: reduce over ic; K -> bf16 [b][h][256][16], V -> bf16 [b][h][16][256] ----------------
__global__ void k_reduce(const float* __restrict__ partial,
                         unsigned short* __restrict__ kt, unsigned short* __restrict__ vt) {
    int gid = blockIdx.x * 256 + threadIdx.x;
    int oc = gid & 127;
    int bp = gid >> 7;          // b*256 + j
    int b = bp >> 8;
    int j = bp & 255;
    const float* p = partial + (size_t)bp * 128 + oc;
    float s = 0.f;
#pragma unroll 8
    for (int ic = 0; ic < 64; ++ic) s += p[(size_t)ic * 65536];
    int h = (oc & 63) >> 4, i = oc & 15;
    if (oc < 64)
        kt[(((size_t)b * 4 + h) * 256 + j) * 16 + i] = bf16b(s);
    else
        vt[(((size_t)b * 4 + h) * 16 + i) * 256 + j] = bf16b(s);
}

// ---------------- K4: fused attention — ONE HEAD PER WAVE, 64 queries/wave ----------------
// grid 4096 = b(2) x 2048 n-blocks of 64; 256 thr (4 waves); wave wv = head wv.
// Every MFMA operand pattern identical in form to verified round-4/7 usage.
__global__ __launch_bounds__(256, 5) void k_attn4(
    const float* __restrict__ x, const unsigned short* __restrict__ wqb,
    const unsigned short* __restrict__ woutb, const unsigned short* __restrict__ kt,
    const unsigned short* __restrict__ vt, float* __restrict__ out)
{
    __shared__ __align__(16) unsigned short s_at[64 * 72];     // x^T [n][c], then att [n][c]
    __shared__ __align__(16) unsigned short s_qp[4][64 * 40];  // per-wave Q then P [n][k]; later yb f32 [64][68]
    __shared__ float s_l[4][64];

    const int tid = threadIdx.x;
    const int b = blockIdx.x >> 11;
    const int n_base = (blockIdx.x & 2047) << 6;
    const int lane = tid & 63;
    const int wv = tid >> 6;     // head index
    const int lc = lane & 15;
    const int lg = lane >> 4;

    unsigned short* qp = s_qp[wv];

    // ---- stage x^T [64][72] cooperatively (verified pattern) ----
    {
        int n_l = tid & 63;
        int c0  = (tid >> 6) * 16;
        const float* xb = x + ((size_t)b << 23) + n_base + n_l;
        uint32* xrow = (uint32*)&s_at[n_l * 72 + c0];
#pragma unroll
        for (int r = 0; r < 8; ++r) {
            float v0 = xb[(size_t)(c0 + 2 * r) << 17];
            float v1 = xb[(size_t)(c0 + 2 * r + 1) << 17];
            xrow[r] = cvtpk(v0, v1);
        }
    }
    // ---- zero own Q pad cols 16..31 (uint32 cols 8..15 of stride-20 rows) ----
    {
        uint32* q32 = (uint32*)qp;
#pragma unroll
        for (int j = 0; j < 8; ++j) q32[lane * 20 + 8 + j] = 0;
    }
    __syncthreads();   // barrier 1: x^T staged

    // ---- Q-proj: wave wv computes Q[n 0..63][i 0..15] of head wv ----
#pragma unroll
    for (int t = 0; t < 4; ++t) {
        floatx4 c = {0.f, 0.f, 0.f, 0.f};
#pragma unroll
        for (int ks = 0; ks < 2; ++ks) {
            short8 a  = *(const short8*)&s_at[(t * 16 + lc) * 72 + ks * 32 + lg * 8];
            short8 bb = *(const short8*)(wqb + (wv * 16 + lc) * 64 + ks * 32 + lg * 8);
            c = __builtin_amdgcn_mfma_f32_16x16x32_bf16(a, bb, c, 0, 0, 0);
        }
#pragma unroll
        for (int r = 0; r < 4; ++r)
            qp[(t * 16 + lg * 4 + r) * 40 + lc] = bf16b(c[r]);
    }
    // ---- hoist Q B-frags to registers (k=32 incl zero pads); frees qp for P ----
    short8 qf[4];
#pragma unroll
    for (int t = 0; t < 4; ++t)
        qf[t] = *(const short8*)&qp[(t * 16 + lc) * 40 + lg * 8];

    __syncthreads();   // barrier 2: all waves' Q-proj x-reads done (att overwrites s_at later)

    // ---- head loop: 8 steps of 32 keys; 3 global loads feed 12 MFMAs per step ----
    const unsigned short* kh = kt + (((size_t)b * 4 + wv) << 12);
    const unsigned short* vh = vt + (((size_t)b * 4 + wv) << 12);
    float lp[4] = {0.f, 0.f, 0.f, 0.f};
    floatx4 pv[4];
#pragma unroll
    for (int t = 0; t < 4; ++t) pv[t] = {0.f, 0.f, 0.f, 0.f};

#pragma unroll 2
    for (int e8 = 0; e8 < 8; ++e8) {
        int j0 = e8 * 32;
        // QK^T: S^T tiles [j 16][n 16] for 4 n-tiles x 2 j-tiles; exp2 in-register; P -> qp[n][j_local]
#pragma unroll
        for (int jt = 0; jt < 2; ++jt) {
            short8 kf = *(const short8*)(kh + (size_t)(j0 + jt * 16 + lc) * 16 + (lg & 1) * 8);
#pragma unroll
            for (int t = 0; t < 4; ++t) {
                floatx4 c = {0.f, 0.f, 0.f, 0.f};
                c = __builtin_amdgcn_mfma_f32_16x16x32_bf16(kf, qf[t], c, 0, 0, 0);
                float p0 = EXP2(c[0]); float p1 = EXP2(c[1]);
                float p2 = EXP2(c[2]); float p3 = EXP2(c[3]);
                lp[t] += (p0 + p1) + (p2 + p3);
                uint32* prow = (uint32*)&qp[(t * 16 + lc) * 40];
                prow[jt * 8 + lg * 2 + 0] = cvtpk(p0, p1);
                prow[jt * 8 + lg * 2 + 1] = cvtpk(p2, p3);
            }
        }
        // PV: one V-frag load shared by 4 MFMAs
        short8 vf = *(const short8*)(vh + (size_t)lc * 256 + j0 + lg * 8);
#pragma unroll
        for (int t = 0; t < 4; ++t) {
            short8 a = *(const short8*)&qp[(t * 16 + lc) * 40 + lg * 8];
            pv[t] = __builtin_amdgcn_mfma_f32_16x16x32_bf16(a, vf, pv[t], 0, 0, 0);
        }
    }

    // ---- softmax denominators; rescale; att -> s_at[n][wv*16 + i] ----
#pragma unroll
    for (int t = 0; t < 4; ++t) {
        lp[t] += __shfl_xor(lp[t], 16, 64);
        lp[t] += __shfl_xor(lp[t], 32, 64);
    }
    if (lane < 16) {
#pragma unroll
        for (int t = 0; t < 4; ++t) s_l[wv][t * 16 + lane] = lp[t];
    }
#pragma unroll
    for (int t = 0; t < 4; ++t) {
#pragma unroll
        for (int r = 0; r < 4; ++r) {
            float rl = RCPF(s_l[wv][t * 16 + lg * 4 + r]);
            s_at[(t * 16 + lg * 4 + r) * 72 + wv * 16 + lc] = bf16b(pv[t][r] * rl);
        }
    }

    __syncthreads();   // barrier 3: att complete, all PV reads of s_qp done

    // ---- out-proj: wave wv -> o-tile wv; yb[o][n] f32 (aliases s_qp) ----
    float* yb = (float*)&s_qp[0][0];   // [64][68] f32 = 17408 B <= 20480 B
#pragma unroll
    for (int t = 0; t < 4; ++t) {
        floatx4 c = {0.f, 0.f, 0.f, 0.f};
#pragma unroll
        for (int ks = 0; ks < 2; ++ks) {
            short8 a  = *(const short8*)&s_at[(t * 16 + lc) * 72 + ks * 32 + lg * 8];
            short8 bb = *(const short8*)(woutb + (wv * 16 + lc) * 64 + ks * 32 + lg * 8);
            c = __builtin_amdgcn_mfma_f32_16x16x32_bf16(a, bb, c, 0, 0, 0);
        }
#pragma unroll
        for (int r = 0; r < 4; ++r)
            yb[(wv * 16 + lc) * 68 + t * 16 + lg * 4 + r] = c[r];
    }
    __syncthreads();   // barrier 4

    // ---- coalesced copyout ----
    {
        int o = tid >> 2, nc = (tid & 3) * 16;
        float* dst = out + ((size_t)b << 23) + (size_t)o * 131072 + n_base + nc;
        const float* src = yb + o * 68 + nc;
#pragma unroll
        for (int i = 0; i < 4; ++i)
            *(float4*)(dst + i * 4) = *(const float4*)(src + i * 4);
    }
}

extern "C" void kernel_launch(void* const* d_in, const int* in_sizes, int n_in,
                              void* d_out, int out_size, void* d_ws, size_t ws_size,
                              hipStream_t stream) {
    const float* x    = (const float*)d_in[0];
    const float* wq   = (const float*)d_in[1];
    const float* wkv  = (const float*)d_in[2];
    const float* wout = (const float*)d_in[3];
    float* out = (float*)d_out;
    float* ws = (float*)d_ws;

    unsigned short* wtb = (unsigned short*)ws;              // [64][128][512] bf16 = 8 MB
    float* partial = ws + 2097152;                          // [64][2][256][128] f32 = 16 MB
    unsigned short* ktu = (unsigned short*)(ws + 6291456);  // [2][4][256][16] bf16
    unsigned short* vtu   = ktu + 32768;                    // [2][4][16][256] bf16
    unsigned short* wqb   = vtu + 32768;                    // [64][64] bf16
    unsigned short* woutb = wqb + 4096;                     // [64][64] bf16

    k_prep_w   <<<16,   256, 0, stream>>>(wq, wout, wqb, woutb);
    k_prep_wkvb<<<4096, 256, 0, stream>>>(wkv, wtb);
    k_conv_mfma<<<512,  256, 0, stream>>>(x, wtb, partial);
    k_reduce   <<<256,  256, 0, stream>>>(partial, ktu, vtu);
    k_attn4    <<<4096, 256, 0, stream>>>(x, wqb, woutb, ktu, vtu, out);
}